// Round 4
// baseline (6191.017 us; speedup 1.0000x reference)
//
#include <hip/hip_runtime.h>
#include <hip/hip_bf16.h>

#define B 32
#define S 512
#define H 1024
#define G 4096          // 4*H
#define LA 8            // lookahead steps for x@W
#define RING 16         // xz ring slots (2*LA)

typedef __attribute__((ext_vector_type(8))) short bf16x8;
typedef __attribute__((ext_vector_type(8))) unsigned short u16x8;
typedef __attribute__((ext_vector_type(4))) float f32x4;

__device__ __forceinline__ unsigned short f2bf(float v) {
    __hip_bfloat16 b = __float2bfloat16(v);
    return *reinterpret_cast<unsigned short*>(&b);
}
__device__ __forceinline__ float bf2f(unsigned short u) {
    union { float f; unsigned int i; } v; v.i = ((unsigned int)u) << 16; return v.f;
}

// =====================================================================
// prep_weights: fragment-ordered bf16 weights for one matrix pair (fw,bw).
// chunk idx = ((blk*4 + w)*16 + f)*64 + lane, 8 bf16 per chunk; 1,048,576 chunks.
//   blk = dir*128 + jg (block owns 32 gate-cols: c = q*8+gj, g = q*H + jg*8 + gj)
//   wave w in [0,4): K-slice w*256; frag f = ks*2+ct (ks in [0,8), ct in [0,2))
//   elem i: kk = w*256 + ks*32 + (lane>>4)*8 + i; col c = ct*16 + (lane&15)
// =====================================================================
__global__ __launch_bounds__(256)
void prep_weights(const float* __restrict__ fw, const float* __restrict__ bw,
                  unsigned short* __restrict__ dst)
{
    size_t idx = (size_t)blockIdx.x * 256 + threadIdx.x;   // 1,048,576
    int lane = idx & 63;
    int f    = (idx >> 6) & 15;
    int w    = (idx >> 10) & 3;
    int blk  = (int)(idx >> 12);           // 0..255
    int dir  = blk >> 7, jg = blk & 127;
    int ks = f >> 1, ct = f & 1;

    int c  = ct * 16 + (lane & 15);
    int g  = (c >> 3) * H + jg * 8 + (c & 7);
    int kk = w * 256 + ks * 32 + ((lane >> 4) * 8);

    const float* src = dir ? bw : fw;
    u16x8 o;
#pragma unroll
    for (int i = 0; i < 8; ++i)
        o[i] = f2bf(src[(size_t)(kk + i) * G + g]);
    *(u16x8*)&dst[idx * 8] = o;
}

// =====================================================================
// prep_x: x fp32 -> bf16 (same [b][s][h] layout)
// =====================================================================
__global__ __launch_bounds__(256)
void prep_x(const float* __restrict__ x, unsigned short* __restrict__ xbf)
{
    size_t i8 = ((size_t)blockIdx.x * 256 + threadIdx.x) * 8;
    float4 v0 = *(const float4*)&x[i8];
    float4 v1 = *(const float4*)&x[i8 + 4];
    u16x8 o;
    o[0] = f2bf(v0.x); o[1] = f2bf(v0.y); o[2] = f2bf(v0.z); o[3] = f2bf(v0.w);
    o[4] = f2bf(v1.x); o[5] = f2bf(v1.y); o[6] = f2bf(v1.z); o[7] = f2bf(v1.w);
    *(u16x8*)&xbf[i8] = o;
}

// =====================================================================
// prologue_xz: fill ring slots 0..LA-1 with xz = x@W + b for step-index tt.
// grid (LA, 128, 2), 256 threads = 4 waves, each wave K-slice w*256.
// =====================================================================
__global__ __launch_bounds__(256)
void prologue_xz(const unsigned short* __restrict__ wbufW,
                 const unsigned short* __restrict__ xbf,
                 unsigned short* __restrict__ xzr,
                 const float* __restrict__ bfw, const float* __restrict__ bbw)
{
    const int tt  = blockIdx.x;        // 0..LA-1
    const int jg  = blockIdx.y;        // 0..127
    const int dir = blockIdx.z;        // 0..1
    const int blk = dir * 128 + jg;
    const int j0  = jg * 8;
    const int tid = threadIdx.x;
    const int wave = tid >> 6;
    const int lane = tid & 63;
    const int s2 = dir ? (S - 1 - tt) : tt;

    __shared__ float red[4][2][16][33];

    const int arow  = lane & 15;
    const int akoff = (lane >> 4) * 8;

    bf16x8 wf[16];
    {
        const unsigned short* base = wbufW + (((size_t)blk * 4 + wave) * 16) * 512 + lane * 8;
#pragma unroll
        for (int f = 0; f < 16; ++f) wf[f] = *(const bf16x8*)(base + f * 512);
    }

    const unsigned short* A0 = xbf + ((size_t)arow * S + s2) * H + wave * 256 + akoff;
    const size_t rstride = (size_t)16 * S * H;

    f32x4 acc00 = {0,0,0,0}, acc01 = {0,0,0,0}, acc10 = {0,0,0,0}, acc11 = {0,0,0,0};
#pragma unroll
    for (int ks = 0; ks < 8; ++ks) {
        bf16x8 a0 = *(const bf16x8*)(A0 + ks * 32);
        bf16x8 a1 = *(const bf16x8*)(A0 + rstride + ks * 32);
        acc00 = __builtin_amdgcn_mfma_f32_16x16x32_bf16(a0, wf[ks*2+0], acc00, 0, 0, 0);
        acc01 = __builtin_amdgcn_mfma_f32_16x16x32_bf16(a0, wf[ks*2+1], acc01, 0, 0, 0);
        acc10 = __builtin_amdgcn_mfma_f32_16x16x32_bf16(a1, wf[ks*2+0], acc10, 0, 0, 0);
        acc11 = __builtin_amdgcn_mfma_f32_16x16x32_bf16(a1, wf[ks*2+1], acc11, 0, 0, 0);
    }
    const int drow = (lane >> 4) * 4, dcol = lane & 15;
#pragma unroll
    for (int r = 0; r < 4; ++r) {
        red[wave][0][drow + r][dcol     ] = acc00[r];
        red[wave][0][drow + r][16 + dcol] = acc01[r];
        red[wave][1][drow + r][dcol     ] = acc10[r];
        red[wave][1][drow + r][16 + dcol] = acc11[r];
    }
    __syncthreads();

    // 256 threads: b = tid>>3, 4 consecutive cols c0..c0+3
    const int b  = tid >> 3;
    const int c0 = (tid & 7) * 4;
    const int bt = b >> 4, row = b & 15;
    const int q = c0 >> 3, gj0 = c0 & 7;
    const float* bsrc = dir ? bbw : bfw;

    unsigned long long packed = 0;
#pragma unroll
    for (int cc = 0; cc < 4; ++cc) {
        int c = c0 + cc;
        float v = bsrc[q * H + j0 + gj0 + cc];
#pragma unroll
        for (int w = 0; w < 4; ++w) v += red[w][bt][row][c];
        packed |= (unsigned long long)f2bf(v) << (16 * cc);
    }
    unsigned short* dst = xzr + (((size_t)tt * 2 + dir) * B + b) * G + q * H + j0 + gj0;
    *(unsigned long long*)dst = packed;
}

// =====================================================================
// lstm_step: ONE step. 256 blocks x 512 threads (8 waves).
// Waves 0-3: h@U (K=1024 in 4 slices) for step t.
// Waves 4-7: x@W (K=1024 in 4 slices) for step t+LA -> ring slot (t+LA)&15.
// Gate phase (tid<256): z = ring[t&15] + sum(hU partials); update state.
// xz phase (tid>=256): ring[(t+LA)&15] = bias + sum(xW partials).
// =====================================================================
__global__ __launch_bounds__(512)
void lstm_step(const unsigned short* __restrict__ wbufU,
               const unsigned short* __restrict__ wbufW,
               const unsigned short* __restrict__ xbf,
               unsigned short* __restrict__ hbf,
               float* __restrict__ hstate, float* __restrict__ cstate,
               unsigned short* __restrict__ xzr,
               const float* __restrict__ pad,
               const float* __restrict__ bfw, const float* __restrict__ bbw,
               float* __restrict__ dout, int t)
{
    const int blk = blockIdx.x;        // 0..255
    const int dir = blk >> 7;
    const int jg  = blk & 127;
    const int j0  = jg * 8;
    const int tid = threadIdx.x;
    const int wave = tid >> 6;
    const int lane = tid & 63;
    const int s = dir ? (S - 1 - t) : t;
    const bool doW = (t + LA) < S;

    __shared__ float red[8][2][16][33];

    const int arow  = lane & 15;
    const int akoff = (lane >> 4) * 8;

    if (wave < 4 || doW) {
        const int w4 = wave & 3;
        const unsigned short* wsrc = (wave < 4) ? wbufU : wbufW;
        const unsigned short* wbase = wsrc + (((size_t)blk * 4 + w4) * 16) * 512 + lane * 8;
        bf16x8 wf[16];
#pragma unroll
        for (int f = 0; f < 16; ++f) wf[f] = *(const bf16x8*)(wbase + f * 512);

        const unsigned short* A0;
        size_t rstride;
        if (wave < 4) {
            A0 = hbf + ((size_t)(dir * B) + arow) * H + w4 * 256 + akoff;
            rstride = (size_t)16 * H;
        } else {
            const int s2 = dir ? (S - 1 - (t + LA)) : (t + LA);
            A0 = xbf + ((size_t)arow * S + s2) * H + w4 * 256 + akoff;
            rstride = (size_t)16 * S * H;
        }

        f32x4 acc00 = {0,0,0,0}, acc01 = {0,0,0,0}, acc10 = {0,0,0,0}, acc11 = {0,0,0,0};
#pragma unroll
        for (int ks = 0; ks < 8; ++ks) {
            bf16x8 a0 = *(const bf16x8*)(A0 + ks * 32);
            bf16x8 a1 = *(const bf16x8*)(A0 + rstride + ks * 32);
            acc00 = __builtin_amdgcn_mfma_f32_16x16x32_bf16(a0, wf[ks*2+0], acc00, 0, 0, 0);
            acc01 = __builtin_amdgcn_mfma_f32_16x16x32_bf16(a0, wf[ks*2+1], acc01, 0, 0, 0);
            acc10 = __builtin_amdgcn_mfma_f32_16x16x32_bf16(a1, wf[ks*2+0], acc10, 0, 0, 0);
            acc11 = __builtin_amdgcn_mfma_f32_16x16x32_bf16(a1, wf[ks*2+1], acc11, 0, 0, 0);
        }
        const int drow = (lane >> 4) * 4, dcol = lane & 15;
#pragma unroll
        for (int r = 0; r < 4; ++r) {
            red[wave][0][drow + r][dcol     ] = acc00[r];
            red[wave][0][drow + r][16 + dcol] = acc01[r];
            red[wave][1][drow + r][dcol     ] = acc10[r];
            red[wave][1][drow + r][16 + dcol] = acc11[r];
        }
    }
    __syncthreads();

    if (tid < 256) {
        // ---- gate phase: one (b, j) cell ----
        const int gj = tid & 7;
        const int gb = (tid >> 3) & 31;
        const int bt = gb >> 4, row = gb & 15;
        const unsigned short* xzrow = xzr + (((size_t)(t & 15) * 2 + dir) * B + gb) * G;

        float z[4];
#pragma unroll
        for (int q = 0; q < 4; ++q) {
            float zz = bf2f(xzrow[q * H + j0 + gj]);
#pragma unroll
            for (int w = 0; w < 4; ++w) zz += red[w][bt][row][q * 8 + gj];
            z[q] = zz;
        }
        float ig = 1.f / (1.f + expf(-z[0]));
        float fg = 1.f / (1.f + expf(-z[1]));
        float gg = tanhf(z[2]);
        float og = 1.f / (1.f + expf(-z[3]));

        const int hidx = dir * B * H + gb * H + j0 + gj;
        float hst = hstate[hidx], cst = cstate[hidx];

        float m  = 1.f - pad[gb * S + s];
        float cn = fg * cst + ig * gg;
        float hn = og * tanhf(cn);
        float h2 = fmaf(m, hn - hst, hst);
        float c2 = fmaf(m, cn - cst, cst);
        hstate[hidx] = h2;
        cstate[hidx] = c2;
        hbf[hidx] = f2bf(h2);

        dout[((size_t)gb * S + s) * (2 * H) + dir * H + j0 + gj] = h2;

        if (t == S - 1) {
            size_t base = (size_t)B * S * 2 * H;
            dout[base + dir * 2 * B * H + gb * H + j0 + gj] = h2;            // h
            dout[base + dir * 2 * B * H + B * H + gb * H + j0 + gj] = c2;    // c
        }
    } else if (doW) {
        // ---- xz phase: write ring slot (t+LA)&15 ----
        const int t2 = tid - 256;
        const int b  = t2 >> 3;
        const int c0 = (t2 & 7) * 4;
        const int bt = b >> 4, row = b & 15;
        const int q = c0 >> 3, gj0 = c0 & 7;
        const float* bsrc = dir ? bbw : bfw;

        unsigned long long packed = 0;
#pragma unroll
        for (int cc = 0; cc < 4; ++cc) {
            int c = c0 + cc;
            float v = bsrc[q * H + j0 + gj0 + cc];
#pragma unroll
            for (int w = 4; w < 8; ++w) v += red[w][bt][row][c];
            packed |= (unsigned long long)f2bf(v) << (16 * cc);
        }
        unsigned short* dst = xzr + (((size_t)((t + LA) & 15) * 2 + dir) * B + b) * G
                            + q * H + j0 + gj0;
        *(unsigned long long*)dst = packed;
    }
}

// =====================================================================
// Host side
// =====================================================================
extern "C" void kernel_launch(void* const* d_in, const int* in_sizes, int n_in,
                              void* d_out, int out_size, void* d_ws, size_t ws_size,
                              hipStream_t stream)
{
    const float* x   = (const float*)d_in[0];
    const float* pad = (const float*)d_in[1];
    const float* Wfw = (const float*)d_in[2];
    const float* Ufw = (const float*)d_in[3];
    const float* bfw = (const float*)d_in[4];
    const float* Wbw = (const float*)d_in[5];
    const float* Ubw = (const float*)d_in[6];
    const float* bbw = (const float*)d_in[7];
    float* out = (float*)d_out;

    char* w = (char*)d_ws;
    unsigned short* wbufW = (unsigned short*)w;                       //  16.8 MB
    unsigned short* wbufU = wbufW + (size_t)1048576 * 8;              //  16.8 MB
    unsigned short* xbf   = wbufU + (size_t)1048576 * 8;              //  33.6 MB
    unsigned short* xzr   = xbf   + (size_t)B * S * H;                //   8.4 MB
    unsigned short* hbf   = xzr   + (size_t)RING * 2 * B * G;         //  128 KB
    float* hstate = (float*)(hbf + (size_t)2 * B * H);                //  256 KB
    float* cstate = hstate + (size_t)2 * B * H;                       //  256 KB

    // zero hbf + hstate + cstate (contiguous, 640 KB)
    hipMemsetAsync(hbf, 0,
                   (size_t)2 * B * H * sizeof(unsigned short) +
                   (size_t)2 * 2 * B * H * sizeof(float), stream);

    prep_x<<<8192, 256, 0, stream>>>(x, xbf);
    prep_weights<<<4096, 256, 0, stream>>>(Wfw, Wbw, wbufW);
    prep_weights<<<4096, 256, 0, stream>>>(Ufw, Ubw, wbufU);
    prologue_xz<<<dim3(LA, 128, 2), 256, 0, stream>>>(wbufW, xbf, xzr, bfw, bbw);

    for (int t = 0; t < S; ++t)
        lstm_step<<<dim3(256), dim3(512), 0, stream>>>(wbufU, wbufW, xbf, hbf,
                                                       hstate, cstate, xzr,
                                                       pad, bfw, bbw, out, t);
}

// Round 5
// 4701.249 us; speedup vs baseline: 1.3169x; 1.3169x over previous
//
#include <hip/hip_runtime.h>
#include <hip/hip_bf16.h>

#define B 32
#define S 512
#define H 1024
#define G 4096          // 4*H
#define NBLK 256

typedef __attribute__((ext_vector_type(8))) short bf16x8;
typedef __attribute__((ext_vector_type(8))) unsigned short u16x8;
typedef __attribute__((ext_vector_type(4))) float f32x4;

__device__ __forceinline__ unsigned short f2bf(float v) {
    __hip_bfloat16 b = __float2bfloat16(v);
    return *reinterpret_cast<unsigned short*>(&b);
}
__device__ __forceinline__ float bf2f(unsigned short u) {
    union { float f; unsigned int i; } v; v.i = ((unsigned int)u) << 16; return v.f;
}
#define MFMA(a, b, c) __builtin_amdgcn_mfma_f32_16x16x32_bf16(a, b, c, 0, 0, 0)

// =====================================================================
// prep_weights: fragment-ordered bf16 weights for one matrix pair (fw,bw).
// chunk idx = ((blk*4 + w)*16 + f)*64 + lane, 8 bf16/chunk; 1,048,576 chunks.
//   blk = dir*128 + jg (block owns 32 cols: c=q*8+gj -> g = q*H + jg*8 + gj)
//   w = K-slice (w*256); frag f = ks*2+ct; elem i: kk = w*256+ks*32+(lane>>4)*8+i,
//   col c = ct*16 + (lane&15)
// =====================================================================
__global__ __launch_bounds__(256)
void prep_weights(const float* __restrict__ fw, const float* __restrict__ bw,
                  unsigned short* __restrict__ dst)
{
    size_t idx = (size_t)blockIdx.x * 256 + threadIdx.x;
    int lane = idx & 63;
    int f    = (idx >> 6) & 15;
    int w    = (idx >> 10) & 3;
    int blk  = (int)(idx >> 12);
    int dir  = blk >> 7, jg = blk & 127;
    int ks = f >> 1, ct = f & 1;

    int c  = ct * 16 + (lane & 15);
    int g  = (c >> 3) * H + jg * 8 + (c & 7);
    int kk = w * 256 + ks * 32 + ((lane >> 4) * 8);

    const float* src = dir ? bw : fw;
    u16x8 o;
#pragma unroll
    for (int i = 0; i < 8; ++i)
        o[i] = f2bf(src[(size_t)(kk + i) * G + g]);
    *(u16x8*)&dst[idx * 8] = o;
}

__global__ __launch_bounds__(256)
void prep_x(const float* __restrict__ x, unsigned short* __restrict__ xbf)
{
    size_t i8 = ((size_t)blockIdx.x * 256 + threadIdx.x) * 8;
    float4 v0 = *(const float4*)&x[i8];
    float4 v1 = *(const float4*)&x[i8 + 4];
    u16x8 o;
    o[0] = f2bf(v0.x); o[1] = f2bf(v0.y); o[2] = f2bf(v0.z); o[3] = f2bf(v0.w);
    o[4] = f2bf(v1.x); o[5] = f2bf(v1.y); o[6] = f2bf(v1.z); o[7] = f2bf(v1.w);
    *(u16x8*)&xbf[i8] = o;
}

// =====================================================================
// lstm_persist: one cooperative kernel runs all 512 steps.
// 256 blocks x 512 threads. Block (dir,jg) owns 32 gate-cols.
// - U slice (64 KB) in LDS, loaded once.
// - Waves 0-3: h@U for step t (K=256 each), A = hbf[(t+1)&1] via agent atomics.
// - Waves 4-7: x@W for future step (t&~3)+4+i, K-slice t&3 per iteration,
//   full-K accumulated in registers; at phase 3 -> bias + bf16 -> LDS ring.
// - Gate (tid<256): ring[t&7] + 4 U partials -> gates -> reg h,c; dout;
//   h republished to hbf[t&1] via 8B agent atomic stores (LLC write-through).
// - Grid barrier: per-block flag line + master(block 0, wave 0) polls all
//   256 flags, publishes generation. Relaxed agent atomics only: no
//   buffer_wbl2 / buffer_inv in the loop (keeps W L2-resident).
// =====================================================================
__global__ __launch_bounds__(512, 1)
void lstm_persist(const unsigned short* __restrict__ wbufU,
                  const unsigned short* __restrict__ wbufW,
                  const unsigned short* __restrict__ xbf,
                  unsigned short* __restrict__ hbf,   // 2 bufs x 65536 shorts
                  unsigned int* __restrict__ flags,   // 256 x 32 uints (128B lines)
                  unsigned int* __restrict__ gen,
                  const float* __restrict__ pad,
                  const float* __restrict__ bfw, const float* __restrict__ bbw,
                  float* __restrict__ dout)
{
    const int blk = blockIdx.x;
    const int dir = blk >> 7;
    const int jg  = blk & 127;
    const int j0  = jg * 8;
    const int tid = threadIdx.x;
    const int wave = tid >> 6;
    const int lane = tid & 63;

    __shared__ short Uw[32768];                  // 64 KB: U frags, LDS-resident
    __shared__ float red[4][2][16][33];          // 16.9 KB: U partials
    __shared__ unsigned short ring[8][32][36];   // 18 KB: xz lookahead (bf16)

    // ---- load U slice into LDS (once) ----
    {
        const unsigned short* src = wbufU + (size_t)blk * 32768;
#pragma unroll
        for (int k = 0; k < 8; ++k) {
            int idx = tid + k * 512;
            *(u16x8*)&Uw[idx * 8] = *(const u16x8*)&src[idx * 8];
        }
    }

    const int arow  = lane & 15;
    const int akoff = (lane >> 4) * 8;
    const int drow  = (lane >> 4) * 4;
    const int dcol  = lane & 15;
    const float* bsrc = dir ? bbw : bfw;

    // per-lane bias for W cols c0=dcol, c1=16+dcol  (g = (c>>3)*H + j0 + (c&7))
    const float wb0 = bsrc[(dcol >> 3) * H + j0 + (dcol & 7)];
    const float wb1 = bsrc[(((16 + dcol) >> 3)) * H + j0 + ((16 + dcol) & 7)];

    // ---- prologue: waves 4-7 compute xz for steps 0..3 (full K) -> ring ----
    if (wave >= 4) {
        const int fs = wave - 4;
        const int s2 = dir ? (S - 1 - fs) : fs;
        f32x4 a00 = {0,0,0,0}, a01 = {0,0,0,0}, a10 = {0,0,0,0}, a11 = {0,0,0,0};
        for (int sl = 0; sl < 4; ++sl) {
            const unsigned short* wbase = wbufW + (((size_t)blk * 4 + sl) * 16) * 512 + lane * 8;
            bf16x8 wf[16];
#pragma unroll
            for (int f = 0; f < 16; ++f) wf[f] = *(const bf16x8*)(wbase + f * 512);
            const unsigned short* A0 = xbf + ((size_t)arow * S + s2) * H + sl * 256 + akoff;
#pragma unroll
            for (int ks = 0; ks < 8; ++ks) {
                bf16x8 x0 = *(const bf16x8*)(A0 + ks * 32);
                bf16x8 x1 = *(const bf16x8*)(A0 + (size_t)16 * S * H + ks * 32);
                a00 = MFMA(x0, wf[ks*2+0], a00); a01 = MFMA(x0, wf[ks*2+1], a01);
                a10 = MFMA(x1, wf[ks*2+0], a10); a11 = MFMA(x1, wf[ks*2+1], a11);
            }
        }
#pragma unroll
        for (int r = 0; r < 4; ++r) {
            ring[fs][drow + r][dcol]           = f2bf(a00[r] + wb0);
            ring[fs][drow + r][16 + dcol]      = f2bf(a01[r] + wb1);
            ring[fs][16 + drow + r][dcol]      = f2bf(a10[r] + wb0);
            ring[fs][16 + drow + r][16 + dcol] = f2bf(a11[r] + wb1);
        }
    }
    __syncthreads();

    // ---- persistent per-thread state ----
    f32x4 w00 = {0,0,0,0}, w01 = {0,0,0,0}, w10 = {0,0,0,0}, w11 = {0,0,0,0};
    float hst = 0.f, cst = 0.f;
    const int gb  = (tid >> 3) & 31;
    const int gj  = tid & 7;
    const int gbt = gb >> 4, grow = gb & 15;
    const f32x4 zero4 = {0,0,0,0};

    for (int t = 0; t < S; ++t) {
        const int s = dir ? (S - 1 - t) : t;
        const int p = t & 3;

        if (wave < 4) {
            // ---- U phase: h(t-1) @ U, K-slice wave*256 ----
            f32x4 u00 = zero4, u01 = zero4, u10 = zero4, u11 = zero4;
            const unsigned short* hb = hbf + ((size_t)((t + 1) & 1)) * 65536
                                     + ((size_t)(dir * B) + arow) * H + wave * 256 + akoff;
#pragma unroll
            for (int ks = 0; ks < 8; ++ks) {
                union { unsigned long long q[2]; bf16x8 v; } ua0, ua1;
                const unsigned long long* p0 = (const unsigned long long*)(hb + ks * 32);
                const unsigned long long* p1 = (const unsigned long long*)(hb + 16 * H + ks * 32);
                ua0.q[0] = __hip_atomic_load(p0,     __ATOMIC_RELAXED, __HIP_MEMORY_SCOPE_AGENT);
                ua0.q[1] = __hip_atomic_load(p0 + 1, __ATOMIC_RELAXED, __HIP_MEMORY_SCOPE_AGENT);
                ua1.q[0] = __hip_atomic_load(p1,     __ATOMIC_RELAXED, __HIP_MEMORY_SCOPE_AGENT);
                ua1.q[1] = __hip_atomic_load(p1 + 1, __ATOMIC_RELAXED, __HIP_MEMORY_SCOPE_AGENT);
                bf16x8 b0 = *(const bf16x8*)&Uw[((wave * 16 + ks * 2 + 0) * 64 + lane) * 8];
                bf16x8 b1 = *(const bf16x8*)&Uw[((wave * 16 + ks * 2 + 1) * 64 + lane) * 8];
                u00 = MFMA(ua0.v, b0, u00); u01 = MFMA(ua0.v, b1, u01);
                u10 = MFMA(ua1.v, b0, u10); u11 = MFMA(ua1.v, b1, u11);
            }
#pragma unroll
            for (int r = 0; r < 4; ++r) {
                red[wave][0][drow + r][dcol]      = u00[r];
                red[wave][0][drow + r][16 + dcol] = u01[r];
                red[wave][1][drow + r][dcol]      = u10[r];
                red[wave][1][drow + r][16 + dcol] = u11[r];
            }
        } else {
            // ---- W phase: K-slice p of xz for future step fs ----
            const int fs = (t & ~3) + 4 + (wave - 4);
            if (fs < S) {
                if (p == 0) { w00 = zero4; w01 = zero4; w10 = zero4; w11 = zero4; }
                const unsigned short* wbase = wbufW + (((size_t)blk * 4 + p) * 16) * 512 + lane * 8;
                bf16x8 wf[16];
#pragma unroll
                for (int f = 0; f < 16; ++f) wf[f] = *(const bf16x8*)(wbase + f * 512);
                const int s2 = dir ? (S - 1 - fs) : fs;
                const unsigned short* A0 = xbf + ((size_t)arow * S + s2) * H + p * 256 + akoff;
#pragma unroll
                for (int ks = 0; ks < 8; ++ks) {
                    bf16x8 x0 = *(const bf16x8*)(A0 + ks * 32);
                    bf16x8 x1 = *(const bf16x8*)(A0 + (size_t)16 * S * H + ks * 32);
                    w00 = MFMA(x0, wf[ks*2+0], w00); w01 = MFMA(x0, wf[ks*2+1], w01);
                    w10 = MFMA(x1, wf[ks*2+0], w10); w11 = MFMA(x1, wf[ks*2+1], w11);
                }
                if (p == 3) {
                    const int slot = fs & 7;
#pragma unroll
                    for (int r = 0; r < 4; ++r) {
                        ring[slot][drow + r][dcol]           = f2bf(w00[r] + wb0);
                        ring[slot][drow + r][16 + dcol]      = f2bf(w01[r] + wb1);
                        ring[slot][16 + drow + r][dcol]      = f2bf(w10[r] + wb0);
                        ring[slot][16 + drow + r][16 + dcol] = f2bf(w11[r] + wb1);
                    }
                }
            }
        }
        __syncthreads();

        // ---- gate phase ----
        if (tid < 256) {
            float z[4];
#pragma unroll
            for (int q = 0; q < 4; ++q) {
                const int c = q * 8 + gj;
                float zz = bf2f(ring[t & 7][gb][c]);
#pragma unroll
                for (int w = 0; w < 4; ++w) zz += red[w][gbt][grow][c];
                z[q] = zz;
            }
            float ig = 1.f / (1.f + expf(-z[0]));
            float fg = 1.f / (1.f + expf(-z[1]));
            float gg = tanhf(z[2]);
            float og = 1.f / (1.f + expf(-z[3]));

            float m  = 1.f - pad[gb * S + s];
            float cn = fg * cst + ig * gg;
            float hn = og * tanhf(cn);
            float h2 = fmaf(m, hn - hst, hst);
            float c2 = fmaf(m, cn - cst, cst);
            hst = h2; cst = c2;

            dout[((size_t)gb * S + s) * (2 * H) + dir * H + j0 + gj] = h2;
            if (t == S - 1) {
                size_t base = (size_t)B * S * 2 * H;
                dout[base + dir * 2 * B * H + gb * H + j0 + gj] = h2;
                dout[base + dir * 2 * B * H + B * H + gb * H + j0 + gj] = c2;
            }

            // pack 4 neighboring h (gj groups of 4) -> one 8B agent-scope store
            unsigned u = (unsigned)f2bf(h2);
            const int gl = lane & ~3;
            unsigned v0 = (unsigned)__shfl((int)u, gl + 0);
            unsigned v1 = (unsigned)__shfl((int)u, gl + 1);
            unsigned v2 = (unsigned)__shfl((int)u, gl + 2);
            unsigned v3 = (unsigned)__shfl((int)u, gl + 3);
            if ((lane & 3) == 0) {
                unsigned long long pk = (unsigned long long)(v0 & 0xffffu)
                                      | ((unsigned long long)(v1 & 0xffffu) << 16)
                                      | ((unsigned long long)(v2 & 0xffffu) << 32)
                                      | ((unsigned long long)(v3 & 0xffffu) << 48);
                unsigned long long* hp = (unsigned long long*)
                    (hbf + ((size_t)(t & 1)) * 65536
                         + ((size_t)(dir * B) + gb) * H + j0 + gj);
                __hip_atomic_store(hp, pk, __ATOMIC_RELAXED, __HIP_MEMORY_SCOPE_AGENT);
            }
        }

        // ---- grid barrier (flags + generation, relaxed agent atomics) ----
        __syncthreads();   // compiler drains vmcnt per-wave before s_barrier
        asm volatile("" ::: "memory");
        if (tid == 0)
            __hip_atomic_store(&flags[blk * 32], (unsigned)(t + 1),
                               __ATOMIC_RELAXED, __HIP_MEMORY_SCOPE_AGENT);
        if (blk == 0) {
            if (wave == 0) {
                bool ok;
                do {
                    ok = true;
#pragma unroll
                    for (int k2 = 0; k2 < 4; ++k2) {
                        unsigned v = __hip_atomic_load(&flags[(lane * 4 + k2) * 32],
                                                       __ATOMIC_RELAXED, __HIP_MEMORY_SCOPE_AGENT);
                        ok = ok && (v >= (unsigned)(t + 1));
                    }
                    if (!ok) __builtin_amdgcn_s_sleep(1);
                } while (!__all(ok));
                if (lane == 0)
                    __hip_atomic_store(gen, (unsigned)(t + 1),
                                       __ATOMIC_RELAXED, __HIP_MEMORY_SCOPE_AGENT);
            }
        } else if (tid == 0) {
            while (__hip_atomic_load(gen, __ATOMIC_RELAXED, __HIP_MEMORY_SCOPE_AGENT)
                   < (unsigned)(t + 1))
                __builtin_amdgcn_s_sleep(2);
        }
        asm volatile("" ::: "memory");
        __syncthreads();
    }
}

// =====================================================================
// Host side
// =====================================================================
extern "C" void kernel_launch(void* const* d_in, const int* in_sizes, int n_in,
                              void* d_out, int out_size, void* d_ws, size_t ws_size,
                              hipStream_t stream)
{
    const float* x   = (const float*)d_in[0];
    const float* pad = (const float*)d_in[1];
    const float* Wfw = (const float*)d_in[2];
    const float* Ufw = (const float*)d_in[3];
    const float* bfw = (const float*)d_in[4];
    const float* Wbw = (const float*)d_in[5];
    const float* Ubw = (const float*)d_in[6];
    const float* bbw = (const float*)d_in[7];
    float* out = (float*)d_out;

    char* w = (char*)d_ws;
    unsigned short* wbufW = (unsigned short*)w;                    // 16 MB
    unsigned short* wbufU = wbufW + (size_t)1048576 * 8;           // 16 MB
    unsigned short* xbf   = wbufU + (size_t)1048576 * 8;           // 32 MB
    unsigned short* hbf   = xbf + (size_t)B * S * H;               // 2 x 128 KB
    unsigned int*   flags = (unsigned int*)(hbf + (size_t)2 * 2 * B * H);  // 32 KB
    unsigned int*   gen   = flags + 256 * 32;                      // 4 B

    // zero hbf (both bufs) + flags + gen each call (deterministic)
    hipMemsetAsync(hbf, 0,
                   (size_t)2 * 2 * B * H * sizeof(unsigned short) +
                   (size_t)(256 * 32 + 32) * sizeof(unsigned int), stream);

    prep_x<<<8192, 256, 0, stream>>>(x, xbf);
    prep_weights<<<4096, 256, 0, stream>>>(Wfw, Wbw, wbufW);
    prep_weights<<<4096, 256, 0, stream>>>(Ufw, Ubw, wbufU);

    void* args[] = { (void*)&wbufU, (void*)&wbufW, (void*)&xbf, (void*)&hbf,
                     (void*)&flags, (void*)&gen, (void*)&pad,
                     (void*)&bfw, (void*)&bbw, (void*)&out };
    hipLaunchCooperativeKernel((void*)lstm_persist, dim3(NBLK), dim3(512),
                               args, 0, stream);
}